// Round 9
// baseline (136.281 us; speedup 1.0000x reference)
//
#include <hip/hip_runtime.h>
#include <hip/hip_bf16.h>
#include <stdint.h>

typedef __attribute__((ext_vector_type(16))) float f32x16;
typedef __attribute__((ext_vector_type(4)))  float f32x4;
typedef __attribute__((ext_vector_type(4), aligned(4))) float f32x4u;  // 4B-aligned vec load
typedef __attribute__((ext_vector_type(8)))  __bf16 bf16x8;

#define CIN 64
#define HW 96
#define PW 98
#define OCH 128
#define NF 54
#define PCH (PW*PW)            // 9604
#define PIMG (CIN*PCH)         // 614656
#define PAD_FLOATS (8*PIMG)    // 4917248
#define PAD_BYTES ((size_t)PAD_FLOATS*4)
#define WB_BYTES ((size_t)CIN*OCH*64*2)   // 1 MiB

// ---------- pad x: [8][64][96][96] -> [8][64][98][98] zero-rimmed
__global__ __launch_bounds__(256) void prep_pad(const float* __restrict__ x,
                                                float* __restrict__ xp) {
    int idx = blockIdx.x*256 + threadIdx.x;    // grid sized exactly
    int pw_ = idx % PW;
    int t   = idx / PW;
    int ph  = t % PW;
    int ic  = t / PW;
    int h = ph - 1, w = pw_ - 1;
    float v = (((unsigned)h < HW) & ((unsigned)w < HW))
            ? x[(size_t)ic*(HW*HW) + h*HW + w] : 0.f;
    xp[idx] = v;
}

// ---------- weight prep: fp32 [oc 128][c 64][54] -> bf16 fragment-native
// elem index = ((c*4 + kc)*2 + hi)*1024 + oc*8 + i   (k = kc*16 + hi*8 + i)
__global__ __launch_bounds__(256) void prep_w(const float* __restrict__ w,
                                              __bf16* __restrict__ wb) {
    int idx = blockIdx.x * 256 + threadIdx.x;   // 262144
    int j  = idx & 31;
    int oc = (idx >> 5) & 127;
    int c  = idx >> 12;
    int k  = 2 * j;
    int kc = k >> 4, hi = (k >> 3) & 1, i = k & 7;
    float v0 = (k     < NF) ? w[(oc*CIN + c)*NF + k    ] : 0.f;
    float v1 = (k + 1 < NF) ? w[(oc*CIN + c)*NF + k + 1] : 0.f;
    size_t off = ((size_t)(c*8 + kc*2 + hi))*1024 + oc*8 + i;
    union { __bf16 b[2]; uint32_t u; } pk;
    pk.b[0] = (__bf16)v0; pk.b[1] = (__bf16)v1;
    *(uint32_t*)((char*)wb + off*2) = pk.u;
}

// cross-product pair tables (PM_cross order)
__device__ __forceinline__ constexpr int PIc(int k) {
    constexpr int t[36] = {0,1,2,3,4,5,6,7, 0,1,2,3,4,5,6, 0,1,2,3,4,5,
                           0,1,2,3,4, 0,1,2,3, 0,1,2, 0,1, 0};
    return t[k];
}
__device__ __forceinline__ constexpr int PJc(int k) {
    constexpr int t[36] = {1,2,3,4,5,6,7,8, 2,3,4,5,6,7,8, 3,4,5,6,7,8,
                           4,5,6,7,8, 5,6,7,8, 6,7,8, 7,8, 8};
    return t[k];
}

// runtime k, fully constant-folds under #pragma unroll
__device__ __forceinline__ float featv(int k, const float* q) {
    return (k < 9)  ? q[k]
         : (k < 18) ? q[k-9] * q[k-9]
         : (k < 54) ? q[PIc(k-18)] * q[PJc(k-18)]
         : 0.f;
}

// build lane's B-fragment for K-group KC (features KC*16+hi*8 .. +7), uniform code
template<int KC>
__device__ __forceinline__ bf16x8 mkfrag(const float* q, int hi) {
    uint32_t P[8];
#pragma unroll
    for (int j = 0; j < 8; j++) {
        union { __bf16 b[2]; uint32_t u; } pk;
        pk.b[0] = (__bf16)featv(KC*16 + 2*j,     q);
        pk.b[1] = (__bf16)featv(KC*16 + 2*j + 1, q);
        P[j] = pk.u;
    }
    union { uint32_t u[4]; bf16x8 v; } t;
#pragma unroll
    for (int j = 0; j < 4; j++) t.u[j] = hi ? P[4+j] : P[j];
    return t.v;
}

// ---------- main (padded): block = 2 waves; wave wv does channels wv*32..+31
// for the same 32 positions x 128 oc; LDS exchange combines the K halves.
// XOR ownership: local acc block os corresponds to GLOBAL oc block (os ^ (wv<<1)).
// All acc subscripts compile-time (rule #20).
// Channel schedule: ALL 16 A-frag loads + R prefetch issue BEFORE the first
// MFMA (MFMA blocks its wave -> loads placed after an MFMA cluster can't
// issue until it retires). #pragma unroll 1 keeps the loop body I-cache-sized.
// mfma_f32_32x32x16_bf16: A/B lane: row/col = lane&31, k = (lane>>5)*8+i;
// D: col = lane&31, row = (reg&3) + 8*(reg>>2) + 4*(lane>>5).
__global__ __launch_bounds__(128, 2) void socg_pad(const float* __restrict__ xp,
                                                   const __bf16* __restrict__ wb,
                                                   float* __restrict__ out) {
    __shared__ __align__(16) char lred[16384];

    const int tid  = threadIdx.x;
    const int lane = tid & 63;
    const int wv   = tid >> 6;
    const int hi   = lane >> 5;
    const int l31  = lane & 31;

    const int bid  = blockIdx.x;        // 2304 = 8 * 288
    const int bimg = bid & 7;           // XCD k -> image k (L2 locality)
    const int rem  = bid >> 3;          // 0..287
    const int h0   = (rem / 6) * 2;
    const int w0   = (rem % 6) * 16;

    const int hA = h0 + (l31 >> 4);
    const int wA = w0 + (l31 & 15);

    const char* xbase = (const char*)(xp + (size_t)bimg*PIMG + (size_t)(wv*32)*PCH);
    const int voff0 = (hA*PW + wA) * 4;

    const __bf16* wcb = wb + (size_t)(wv*32)*(OCH*64);
    const int wsel = wv << 1;           // XOR remap of oc blocks per wave

    f32x16 acc[4];
#pragma unroll
    for (int os = 0; os < 4; os++)
#pragma unroll
        for (int r = 0; r < 16; r++) acc[os][r] = 0.f;

    f32x4 R0[3], R1[3];
#pragma unroll
    for (int rr = 0; rr < 3; rr++)
        R0[rr] = (f32x4)*(const f32x4u*)(xbase + voff0 + rr*(PW*4));

    // A-fragment loader: local os -> global oc block (os ^ wsel). os compile-time.
    auto loadA = [&](bf16x8 (&A)[4], const __bf16* wc_, int kc) {
#pragma unroll
        for (int os = 0; os < 4; os++) {
            const int gblk = os ^ wsel;
            A[os] = *(const bf16x8*)(wc_ + (kc*2 + hi)*1024 + (gblk*32 + l31)*8);
        }
    };

    auto body = [&](f32x4 (&Rc)[3], f32x4 (&Rn)[3], int cc) {
        const __bf16* wc_ = wcb + (size_t)cc * (OCH*64);
        // ---- issue EVERYTHING first: 16 A-frag loads + 3 R-prefetch loads
        bf16x8 A0[4], A1[4], A2[4], A3[4];
        loadA(A0, wc_, 0);
        loadA(A1, wc_, 1);
        loadA(A2, wc_, 2);
        loadA(A3, wc_, 3);
        if (cc + 1 < 32) {
            const int vo = voff0 + (cc + 1)*(PCH*4);
#pragma unroll
            for (int rr = 0; rr < 3; rr++)
                Rn[rr] = (f32x4)*(const f32x4u*)(xbase + vo + rr*(PW*4));
        }
        // ---- feature build + MFMA (loads draining underneath)
        float q[9];
#pragma unroll
        for (int rr = 0; rr < 3; rr++) {
            q[rr*3 + 0] = Rc[rr][0];
            q[rr*3 + 1] = Rc[rr][1];
            q[rr*3 + 2] = Rc[rr][2];
        }
        {
            bf16x8 tb = mkfrag<0>(q, hi);
#pragma unroll
            for (int os = 0; os < 4; os++)
                acc[os] = __builtin_amdgcn_mfma_f32_32x32x16_bf16(A0[os], tb,
                                                                  acc[os], 0, 0, 0);
        }
        {
            bf16x8 tb = mkfrag<1>(q, hi);
#pragma unroll
            for (int os = 0; os < 4; os++)
                acc[os] = __builtin_amdgcn_mfma_f32_32x32x16_bf16(A1[os], tb,
                                                                  acc[os], 0, 0, 0);
        }
        {
            bf16x8 tb = mkfrag<2>(q, hi);
#pragma unroll
            for (int os = 0; os < 4; os++)
                acc[os] = __builtin_amdgcn_mfma_f32_32x32x16_bf16(A2[os], tb,
                                                                  acc[os], 0, 0, 0);
        }
        {
            bf16x8 tb = mkfrag<3>(q, hi);
#pragma unroll
            for (int os = 0; os < 4; os++)
                acc[os] = __builtin_amdgcn_mfma_f32_32x32x16_bf16(A3[os], tb,
                                                                  acc[os], 0, 0, 0);
        }
    };

#pragma unroll 1
    for (int c2 = 0; c2 < 32; c2 += 2) {
        body(R0, R1, c2);
        body(R1, R0, c2 + 1);
    }

    // ---- K-split combine. Each wave STORES local acc[2],acc[3] (the other
    // wave's oc blocks) and ADDS the partner's contribution into acc[0],acc[1].
    // All indices compile-time; lane*16 layout -> no bank conflicts.
    {
        char* my = lred + wv*8192;
#pragma unroll
        for (int g = 0; g < 8; g++) {
            f32x4 v;
            v[0] = acc[2 + (g>>2)][(g&3)*4 + 0];
            v[1] = acc[2 + (g>>2)][(g&3)*4 + 1];
            v[2] = acc[2 + (g>>2)][(g&3)*4 + 2];
            v[3] = acc[2 + (g>>2)][(g&3)*4 + 3];
            *(f32x4*)(my + g*1024 + lane*16) = v;
        }
        __syncthreads();
        const char* ot = lred + (wv^1)*8192;
#pragma unroll
        for (int g = 0; g < 8; g++) {
            f32x4 v = *(const f32x4*)(ot + g*1024 + lane*16);
            acc[g>>2][(g&3)*4 + 0] += v[0];
            acc[g>>2][(g&3)*4 + 1] += v[1];
            acc[g>>2][(g&3)*4 + 2] += v[2];
            acc[g>>2][(g&3)*4 + 3] += v[3];
        }
    }

    // epilogue: write local acc[0],acc[1] -> global oc blocks (osl ^ wsel)
    const size_t obase = (size_t)bimg*OCH*HW*HW + (size_t)hA*HW + wA;
#pragma unroll
    for (int osl = 0; osl < 2; osl++) {
        const int gblk = osl ^ wsel;
#pragma unroll
        for (int r = 0; r < 16; r++) {
            int oc = gblk*32 + (r & 3) + 8*(r >> 2) + 4*hi;
            out[obase + (size_t)oc*(HW*HW)] = acc[osl][r];
        }
    }
}

// ---------- fallback (no pad buffer): register-path kernel, weights at ws+0
__global__ __launch_bounds__(64, 3) void socg_fb(const float* __restrict__ x,
                                                 const __bf16* __restrict__ wb,
                                                 float* __restrict__ out) {
    const int lane = threadIdx.x;
    const int hi   = lane >> 5;
    const int l31  = lane & 31;

    const int bid  = blockIdx.x;
    const int bimg = bid / 288;
    const int rem  = bid - bimg * 288;
    const int h0   = (rem / 6) * 2;
    const int w0   = (rem % 6) * 16;

    const int hA = h0 + (l31 >> 4);
    const int wA = w0 + (l31 & 15);

    int   off[9];
    float msk[9];
#pragma unroll
    for (int rr = 0; rr < 3; rr++)
#pragma unroll
        for (int cc = 0; cc < 3; cc++) {
            int hh = hA - 1 + rr, ww = wA - 1 + cc;
            bool ok = ((unsigned)hh < HW) && ((unsigned)ww < HW);
            int hc = hh < 0 ? 0 : (hh > HW-1 ? HW-1 : hh);
            int wc = ww < 0 ? 0 : (ww > HW-1 ? HW-1 : ww);
            off[rr*3 + cc] = hc * HW + wc;
            msk[rr*3 + cc] = ok ? 1.f : 0.f;
        }

    const float* xb = x + (size_t)bimg * CIN * HW * HW;

    f32x16 acc[4];
#pragma unroll
    for (int os = 0; os < 4; os++)
#pragma unroll
        for (int r = 0; r < 16; r++) acc[os][r] = 0.f;

    float rA[9], rB[9];
#pragma unroll
    for (int i = 0; i < 9; i++) rA[i] = xb[off[i]];

    auto loadA = [&](bf16x8 (&A)[4], const __bf16* wc_, int kc) {
#pragma unroll
        for (int os = 0; os < 4; os++)
            A[os] = *(const bf16x8*)(wc_ + (kc*2 + hi)*1024 + (os*32 + l31)*8);
    };

    auto body = [&](float (&rc)[9], float (&rn)[9], int c) {
        const __bf16* wc_ = wb + (size_t)c * 8192;
        bf16x8 A0[4], A1[4], A2[4], A3[4];
        loadA(A0, wc_, 0);
        loadA(A1, wc_, 1);
        loadA(A2, wc_, 2);
        loadA(A3, wc_, 3);
        if (c + 1 < CIN) {
            const float* xn = xb + (size_t)(c + 1) * HW * HW;
#pragma unroll
            for (int i = 0; i < 9; i++) rn[i] = xn[off[i]];
        }
        float q[9];
#pragma unroll
        for (int i = 0; i < 9; i++) q[i] = rc[i] * msk[i];

        {
            bf16x8 tb = mkfrag<0>(q, hi);
#pragma unroll
            for (int os = 0; os < 4; os++)
                acc[os] = __builtin_amdgcn_mfma_f32_32x32x16_bf16(A0[os], tb,
                                                                  acc[os], 0, 0, 0);
        }
        {
            bf16x8 tb = mkfrag<1>(q, hi);
#pragma unroll
            for (int os = 0; os < 4; os++)
                acc[os] = __builtin_amdgcn_mfma_f32_32x32x16_bf16(A1[os], tb,
                                                                  acc[os], 0, 0, 0);
        }
        {
            bf16x8 tb = mkfrag<2>(q, hi);
#pragma unroll
            for (int os = 0; os < 4; os++)
                acc[os] = __builtin_amdgcn_mfma_f32_32x32x16_bf16(A2[os], tb,
                                                                  acc[os], 0, 0, 0);
        }
        {
            bf16x8 tb = mkfrag<3>(q, hi);
#pragma unroll
            for (int os = 0; os < 4; os++)
                acc[os] = __builtin_amdgcn_mfma_f32_32x32x16_bf16(A3[os], tb,
                                                                  acc[os], 0, 0, 0);
        }
    };

#pragma unroll 1
    for (int c2 = 0; c2 < CIN; c2 += 2) {
        body(rA, rB, c2);
        body(rB, rA, c2 + 1);
    }

#pragma unroll
    for (int os = 0; os < 4; os++)
#pragma unroll
        for (int r = 0; r < 16; r++) {
            int oc = os*32 + (r & 3) + 8*(r >> 2) + 4*hi;
            out[(((size_t)bimg*OCH + oc)*HW + hA)*HW + wA] = acc[os][r];
        }
}

extern "C" void kernel_launch(void* const* d_in, const int* in_sizes, int n_in,
                              void* d_out, int out_size, void* d_ws, size_t ws_size,
                              hipStream_t stream) {
    const float* x = (const float*)d_in[0];
    const float* w = (const float*)d_in[1];
    float* out = (float*)d_out;
    if (ws_size >= PAD_BYTES + WB_BYTES) {
        float* xpad = (float*)d_ws;
        __bf16* wbf = (__bf16*)((char*)d_ws + PAD_BYTES);
        hipLaunchKernelGGL(prep_pad, dim3(PAD_FLOATS/256), dim3(256), 0, stream, x, xpad);
        hipLaunchKernelGGL(prep_w, dim3(1024), dim3(256), 0, stream, w, wbf);
        hipLaunchKernelGGL(socg_pad, dim3(2304), dim3(128), 0, stream, xpad, wbf, out);
    } else {
        __bf16* wbf = (__bf16*)d_ws;
        hipLaunchKernelGGL(prep_w, dim3(1024), dim3(256), 0, stream, w, wbf);
        hipLaunchKernelGGL(socg_fb, dim3(2304), dim3(64), 0, stream, x, wbf, out);
    }
}

// Round 10
// 129.421 us; speedup vs baseline: 1.0530x; 1.0530x over previous
//
#include <hip/hip_runtime.h>
#include <hip/hip_bf16.h>
#include <stdint.h>

typedef __attribute__((ext_vector_type(16))) float f32x16;
typedef __attribute__((ext_vector_type(4)))  float f32x4;
typedef __attribute__((ext_vector_type(4), aligned(4))) float f32x4u;  // 4B-aligned vec load
typedef __attribute__((ext_vector_type(8)))  __bf16 bf16x8;

#define CIN 64
#define HW 96
#define PW 98
#define OCH 128
#define NF 54
#define PCH (PW*PW)            // 9604
#define PIMG (CIN*PCH)         // 614656
#define PAD_FLOATS (8*PIMG)    // 4917248
#define PAD_BYTES ((size_t)PAD_FLOATS*4)
#define CHB 16384              // bytes per channel weight slab (128 oc x 64 k x 2B)
#define WB_BYTES ((size_t)CIN*CHB)   // 1 MiB

// ---------- pad x: [8][64][96][96] -> [8][64][98][98] zero-rimmed
__global__ __launch_bounds__(256) void prep_pad(const float* __restrict__ x,
                                                float* __restrict__ xp) {
    int idx = blockIdx.x*256 + threadIdx.x;    // grid sized exactly
    int pw_ = idx % PW;
    int t   = idx / PW;
    int ph  = t % PW;
    int ic  = t / PW;
    int h = ph - 1, w = pw_ - 1;
    float v = (((unsigned)h < HW) & ((unsigned)w < HW))
            ? x[(size_t)ic*(HW*HW) + h*HW + w] : 0.f;
    xp[idx] = v;
}

// ---------- weight prep: fp32 [oc 128][c 64][54] -> bf16 fragment-native
// elem index = ((c*4 + kc)*2 + hi)*1024 + oc*8 + i   (k = kc*16 + hi*8 + i)
__global__ __launch_bounds__(256) void prep_w(const float* __restrict__ w,
                                              __bf16* __restrict__ wb) {
    int idx = blockIdx.x * 256 + threadIdx.x;   // 262144
    int j  = idx & 31;
    int oc = (idx >> 5) & 127;
    int c  = idx >> 12;
    int k  = 2 * j;
    int kc = k >> 4, hi = (k >> 3) & 1, i = k & 7;
    float v0 = (k     < NF) ? w[(oc*CIN + c)*NF + k    ] : 0.f;
    float v1 = (k + 1 < NF) ? w[(oc*CIN + c)*NF + k + 1] : 0.f;
    size_t off = ((size_t)(c*8 + kc*2 + hi))*1024 + oc*8 + i;
    union { __bf16 b[2]; uint32_t u; } pk;
    pk.b[0] = (__bf16)v0; pk.b[1] = (__bf16)v1;
    *(uint32_t*)((char*)wb + off*2) = pk.u;
}

// cross-product pair tables (PM_cross order)
__device__ __forceinline__ constexpr int PIc(int k) {
    constexpr int t[36] = {0,1,2,3,4,5,6,7, 0,1,2,3,4,5,6, 0,1,2,3,4,5,
                           0,1,2,3,4, 0,1,2,3, 0,1,2, 0,1, 0};
    return t[k];
}
__device__ __forceinline__ constexpr int PJc(int k) {
    constexpr int t[36] = {1,2,3,4,5,6,7,8, 2,3,4,5,6,7,8, 3,4,5,6,7,8,
                           4,5,6,7,8, 5,6,7,8, 6,7,8, 7,8, 8};
    return t[k];
}

// runtime k, fully constant-folds under #pragma unroll
__device__ __forceinline__ float featv(int k, const float* q) {
    return (k < 9)  ? q[k]
         : (k < 18) ? q[k-9] * q[k-9]
         : (k < 54) ? q[PIc(k-18)] * q[PJc(k-18)]
         : 0.f;
}

// build lane's B-fragment for K-group KC (features KC*16+hi*8 .. +7), uniform code
template<int KC>
__device__ __forceinline__ bf16x8 mkfrag(const float* q, int hi) {
    uint32_t P[8];
#pragma unroll
    for (int j = 0; j < 8; j++) {
        union { __bf16 b[2]; uint32_t u; } pk;
        pk.b[0] = (__bf16)featv(KC*16 + 2*j,     q);
        pk.b[1] = (__bf16)featv(KC*16 + 2*j + 1, q);
        P[j] = pk.u;
    }
    union { uint32_t u[4]; bf16x8 v; } t;
#pragma unroll
    for (int j = 0; j < 4; j++) t.u[j] = hi ? P[4+j] : P[j];
    return t.v;
}

__device__ __forceinline__ void gload_lds16(const void* g, void* l) {
    __builtin_amdgcn_global_load_lds(
        (const __attribute__((address_space(1))) void*)g,
        (__attribute__((address_space(3))) void*)l, 16, 0, 0);
}

// ---------- main (padded + LDS-shared weights): block = 4 waves, 128 pos x 128 oc.
// All 4 waves consume the SAME channel weight slab, staged once per block into
// LDS (double-buffered, 1 barrier/channel) -> global weight traffic /4 vs the
// per-wave refetch design (which was L1/L2-BW-bound at ~2150 cyc/channel).
// mfma_f32_32x32x16_bf16: A/B lane: row/col = lane&31, k = (lane>>5)*8+i;
// D: col = lane&31, row = (reg&3) + 8*(reg>>2) + 4*(lane>>5).
__global__ __launch_bounds__(256, 2) void socg_lds(const float* __restrict__ xp,
                                                   const __bf16* __restrict__ wb,
                                                   float* __restrict__ out) {
    __shared__ __align__(16) char sw[2][CHB];   // 32 KiB

    const int tid  = threadIdx.x;
    const int lane = tid & 63;
    const int wv   = tid >> 6;
    const int hi   = lane >> 5;
    const int l31  = lane & 31;

    const int bid  = blockIdx.x;        // 576 = 8 imgs * 72
    const int bimg = bid & 7;           // XCD k -> image k (L2 locality)
    const int rem  = bid >> 3;          // 0..71
    const int h0   = (rem / 6) * 8;     // block tile: 8 rows x 16 cols
    const int w0   = (rem % 6) * 16;

    const int hA = h0 + wv*2 + (l31 >> 4);   // wave owns rows wv*2, wv*2+1
    const int wA = w0 + (l31 & 15);

    const char* xbase = (const char*)(xp + (size_t)bimg*PIMG);
    const int voff0 = (hA*PW + wA) * 4;

    f32x16 acc[4];
#pragma unroll
    for (int os = 0; os < 4; os++)
#pragma unroll
        for (int r = 0; r < 16; r++) acc[os][r] = 0.f;

    // stage channel 0 weights; load channel 0 window
    {
        const char* wsrc = (const char*)wb;
#pragma unroll
        for (int i = 0; i < 4; i++) {
            const int m = i*4 + wv;
            gload_lds16(wsrc + m*1024 + lane*16, &sw[0][0] + m*1024);
        }
    }
    f32x4 R0[3], R1[3];
#pragma unroll
    for (int rr = 0; rr < 3; rr++)
        R0[rr] = (f32x4)*(const f32x4u*)(xbase + voff0 + rr*(PW*4));
    __syncthreads();   // stage(0) landed (barrier drains vmcnt)

    auto chan = [&](f32x4 (&Rc)[3], f32x4 (&Rn)[3], int c) {
        char* bufc = &sw[0][0] + ((c    ) & 1) * CHB;
        char* bufn = &sw[0][0] + ((c + 1) & 1) * CHB;
        // 1) issue next-channel staging + R prefetch (longest latency first)
        if (c + 1 < CIN) {
            const char* wsrc = (const char*)wb + (size_t)(c + 1)*CHB;
#pragma unroll
            for (int i = 0; i < 4; i++) {
                const int m = i*4 + wv;
                gload_lds16(wsrc + m*1024 + lane*16, bufn + m*1024);
            }
            const char* xn = xbase + (size_t)(c + 1)*(PCH*4);
#pragma unroll
            for (int rr = 0; rr < 3; rr++)
                Rn[rr] = (f32x4)*(const f32x4u*)(xn + voff0 + rr*(PW*4));
        }
        // 2) issue ALL 16 A-frag ds_reads (latency hides under build+MFMA)
        bf16x8 A0[4], A1[4], A2[4], A3[4];
#pragma unroll
        for (int os = 0; os < 4; os++) {
            const int co = (os*32 + l31)*16;
            A0[os] = *(const bf16x8*)(bufc + (0*2 + hi)*2048 + co);
            A1[os] = *(const bf16x8*)(bufc + (1*2 + hi)*2048 + co);
            A2[os] = *(const bf16x8*)(bufc + (2*2 + hi)*2048 + co);
            A3[os] = *(const bf16x8*)(bufc + (3*2 + hi)*2048 + co);
        }
        // 3) feature build + MFMA
        float q[9];
#pragma unroll
        for (int rr = 0; rr < 3; rr++) {
            q[rr*3 + 0] = Rc[rr][0];
            q[rr*3 + 1] = Rc[rr][1];
            q[rr*3 + 2] = Rc[rr][2];
        }
        {
            bf16x8 tb = mkfrag<0>(q, hi);
#pragma unroll
            for (int os = 0; os < 4; os++)
                acc[os] = __builtin_amdgcn_mfma_f32_32x32x16_bf16(A0[os], tb,
                                                                  acc[os], 0, 0, 0);
        }
        {
            bf16x8 tb = mkfrag<1>(q, hi);
#pragma unroll
            for (int os = 0; os < 4; os++)
                acc[os] = __builtin_amdgcn_mfma_f32_32x32x16_bf16(A1[os], tb,
                                                                  acc[os], 0, 0, 0);
        }
        {
            bf16x8 tb = mkfrag<2>(q, hi);
#pragma unroll
            for (int os = 0; os < 4; os++)
                acc[os] = __builtin_amdgcn_mfma_f32_32x32x16_bf16(A2[os], tb,
                                                                  acc[os], 0, 0, 0);
        }
        {
            bf16x8 tb = mkfrag<3>(q, hi);
#pragma unroll
            for (int os = 0; os < 4; os++)
                acc[os] = __builtin_amdgcn_mfma_f32_32x32x16_bf16(A3[os], tb,
                                                                  acc[os], 0, 0, 0);
        }
        // 4) barrier: my reads of bufc done (lgkm drained) + stage(c+1) landed
        __syncthreads();
    };

#pragma unroll 1
    for (int c2 = 0; c2 < CIN; c2 += 2) {
        chan(R0, R1, c2);
        chan(R1, R0, c2 + 1);
    }

    // epilogue: D col = pos (lane&31), row = (r&3) + 8*(r>>2) + 4*hi
    const size_t obase = (size_t)bimg*OCH*HW*HW + (size_t)hA*HW + wA;
#pragma unroll
    for (int os = 0; os < 4; os++)
#pragma unroll
        for (int r = 0; r < 16; r++) {
            const int oc = os*32 + (r & 3) + 8*(r >> 2) + 4*hi;
            out[obase + (size_t)oc*(HW*HW)] = acc[os][r];
        }
}

// ---------- fallback (no pad buffer): round-8 register-path kernel
__global__ __launch_bounds__(64, 3) void socg_fb(const float* __restrict__ x,
                                                 const __bf16* __restrict__ wb,
                                                 float* __restrict__ out) {
    const int lane = threadIdx.x;
    const int hi   = lane >> 5;
    const int l31  = lane & 31;

    const int bid  = blockIdx.x;
    const int bimg = bid / 288;
    const int rem  = bid - bimg * 288;
    const int h0   = (rem / 6) * 2;
    const int w0   = (rem % 6) * 16;

    const int hA = h0 + (l31 >> 4);
    const int wA = w0 + (l31 & 15);

    int   off[9];
    float msk[9];
#pragma unroll
    for (int rr = 0; rr < 3; rr++)
#pragma unroll
        for (int cc = 0; cc < 3; cc++) {
            int hh = hA - 1 + rr, ww = wA - 1 + cc;
            bool ok = ((unsigned)hh < HW) && ((unsigned)ww < HW);
            int hc = hh < 0 ? 0 : (hh > HW-1 ? HW-1 : hh);
            int wc = ww < 0 ? 0 : (ww > HW-1 ? HW-1 : ww);
            off[rr*3 + cc] = hc * HW + wc;
            msk[rr*3 + cc] = ok ? 1.f : 0.f;
        }

    const float* xb = x + (size_t)bimg * CIN * HW * HW;

    f32x16 acc[4];
#pragma unroll
    for (int os = 0; os < 4; os++)
#pragma unroll
        for (int r = 0; r < 16; r++) acc[os][r] = 0.f;

    float rA[9], rB[9];
#pragma unroll
    for (int i = 0; i < 9; i++) rA[i] = xb[off[i]];

    auto loadA = [&](bf16x8 (&A)[4], const __bf16* wc_, int kc) {
#pragma unroll
        for (int os = 0; os < 4; os++)
            A[os] = *(const bf16x8*)(wc_ + (kc*2 + hi)*1024 + (os*32 + l31)*8);
    };

    auto body = [&](float (&rc)[9], float (&rn)[9], int c) {
        const __bf16* wc_ = wb + (size_t)c * 8192;
        bf16x8 A0[4], A1[4], A2[4], A3[4];
        loadA(A0, wc_, 0);
        loadA(A1, wc_, 1);
        loadA(A2, wc_, 2);
        loadA(A3, wc_, 3);
        if (c + 1 < CIN) {
            const float* xn = xb + (size_t)(c + 1) * HW * HW;
#pragma unroll
            for (int i = 0; i < 9; i++) rn[i] = xn[off[i]];
        }
        float q[9];
#pragma unroll
        for (int i = 0; i < 9; i++) q[i] = rc[i] * msk[i];

        {
            bf16x8 tb = mkfrag<0>(q, hi);
#pragma unroll
            for (int os = 0; os < 4; os++)
                acc[os] = __builtin_amdgcn_mfma_f32_32x32x16_bf16(A0[os], tb,
                                                                  acc[os], 0, 0, 0);
        }
        {
            bf16x8 tb = mkfrag<1>(q, hi);
#pragma unroll
            for (int os = 0; os < 4; os++)
                acc[os] = __builtin_amdgcn_mfma_f32_32x32x16_bf16(A1[os], tb,
                                                                  acc[os], 0, 0, 0);
        }
        {
            bf16x8 tb = mkfrag<2>(q, hi);
#pragma unroll
            for (int os = 0; os < 4; os++)
                acc[os] = __builtin_amdgcn_mfma_f32_32x32x16_bf16(A2[os], tb,
                                                                  acc[os], 0, 0, 0);
        }
        {
            bf16x8 tb = mkfrag<3>(q, hi);
#pragma unroll
            for (int os = 0; os < 4; os++)
                acc[os] = __builtin_amdgcn_mfma_f32_32x32x16_bf16(A3[os], tb,
                                                                  acc[os], 0, 0, 0);
        }
    };

#pragma unroll 1
    for (int c2 = 0; c2 < CIN; c2 += 2) {
        body(rA, rB, c2);
        body(rB, rA, c2 + 1);
    }

#pragma unroll
    for (int os = 0; os < 4; os++)
#pragma unroll
        for (int r = 0; r < 16; r++) {
            int oc = os*32 + (r & 3) + 8*(r >> 2) + 4*hi;
            out[(((size_t)bimg*OCH + oc)*HW + hA)*HW + wA] = acc[os][r];
        }
}

extern "C" void kernel_launch(void* const* d_in, const int* in_sizes, int n_in,
                              void* d_out, int out_size, void* d_ws, size_t ws_size,
                              hipStream_t stream) {
    const float* x = (const float*)d_in[0];
    const float* w = (const float*)d_in[1];
    float* out = (float*)d_out;
    if (ws_size >= PAD_BYTES + WB_BYTES) {
        float* xpad = (float*)d_ws;
        __bf16* wbf = (__bf16*)((char*)d_ws + PAD_BYTES);
        hipLaunchKernelGGL(prep_pad, dim3(PAD_FLOATS/256), dim3(256), 0, stream, x, xpad);
        hipLaunchKernelGGL(prep_w, dim3(1024), dim3(256), 0, stream, w, wbf);
        hipLaunchKernelGGL(socg_lds, dim3(576), dim3(256), 0, stream, xpad, wbf, out);
    } else {
        __bf16* wbf = (__bf16*)d_ws;
        hipLaunchKernelGGL(prep_w, dim3(1024), dim3(256), 0, stream, w, wbf);
        hipLaunchKernelGGL(socg_fb, dim3(2304), dim3(64), 0, stream, x, wbf, out);
    }
}